// Round 5
// baseline (349.381 us; speedup 1.0000x reference)
//
#include <hip/hip_runtime.h>
#include <cstdint>
#include <cmath>

// Binarized MLP via i8 MFMA: 16384x1024 -> 2048 -> 2048 -> 2048 -> 2.
// R9 = R5 (verified 97us/layer schedule: 256x256 tile, 8 waves 2m x 4n,
// double-buffered 128KB LDS, 4 phases/K-tile, 2 barriers/phase, prefetch in
// phases 0-1, vmcnt(0) drain at tile end) with ONE change:
// mfma_i32_16x16x64_i8 -> mfma_i32_32x32x32_i8 (4404 vs 3944 TOPS ubench,
// half the MFMA instruction count at identical LDS traffic).
// Wave tile 128x64 = 4(m) x 2(n) tiles of 32x32; K-tile 128B = 4 ksteps of
// 32B. A/B frag: row|col=lane&31, k=(lane>>5)*16+byte -> logical chunk
// ks*2+(lane>>5), phys chunk ^(row&7). C/D: col=lane&31,
// row=(reg&3)+8*(reg>>2)+4*(lane>>5), 16 regs.
// Staging keeps the XOR-(row&7) pre-swizzled source (0 bank conflicts).

typedef int i32x4 __attribute__((ext_vector_type(4)));
typedef int i32x16 __attribute__((ext_vector_type(16)));

static constexpr int Bsz = 16384;
static constexpr int Din = 1024;
static constexpr int Hid = 2048;

__device__ __forceinline__ void ld16(const void* g, void* l) {
  __builtin_amdgcn_global_load_lds(
      (const __attribute__((address_space(1))) void*)g,
      (__attribute__((address_space(3))) void*)l, 16, 0, 0);
}

// ---------------- fused prep: all sign-quantizations + BN folds ------------
__global__ void prep_kernel(
    const float* __restrict__ x, const float* __restrict__ w1,
    const float* __restrict__ w2, const float* __restrict__ w3,
    const float* __restrict__ g1, const float* __restrict__ b1,
    const float* __restrict__ m1, const float* __restrict__ v1,
    const float* __restrict__ g2, const float* __restrict__ b2,
    const float* __restrict__ m2, const float* __restrict__ v2,
    const float* __restrict__ g3, const float* __restrict__ b3,
    const float* __restrict__ m3, const float* __restrict__ v3,
    char* __restrict__ A0, char* __restrict__ W1s,
    char* __restrict__ W2s, char* __restrict__ W3s,
    float* __restrict__ a1, float* __restrict__ be1,
    float* __restrict__ a2, float* __restrict__ be2,
    float* __restrict__ a3, float* __restrict__ be3) {
  constexpr int BX = 16384, BW1 = 2048, BW2 = 4096, BW3 = 4096;
  const int blk = blockIdx.x;
  if (blk < BX + BW1 + BW2 + BW3) {
    const float* s;
    char* d;
    float thr = 0.0f;
    int rb;
    if (blk < BX) {
      s = x; d = A0; thr = 0.5f; rb = 0;
    } else if (blk < BX + BW1) {
      s = w1; d = W1s; rb = BX;
    } else if (blk < BX + BW1 + BW2) {
      s = w2; d = W2s; rb = BX + BW1;
    } else {
      s = w3; d = W3s; rb = BX + BW1 + BW2;
    }
    int i = (blk - rb) * 256 + threadIdx.x;
    float4 v = ((const float4*)s)[i];
    char4 o;
    o.x = (v.x >= thr) ? 1 : -1;
    o.y = (v.y >= thr) ? 1 : -1;
    o.z = (v.z >= thr) ? 1 : -1;
    o.w = (v.w >= thr) ? 1 : -1;
    ((char4*)d)[i] = o;
  } else {
    int t = (blk - (BX + BW1 + BW2 + BW3)) * 256 + threadIdx.x;  // 0..6143
    int l = t >> 11, e = t & 2047;
    const float *g, *b, *m, *v;
    float *al, *be;
    if (l == 0) { g = g1; b = b1; m = m1; v = v1; al = a1; be = be1; }
    else if (l == 1) { g = g2; b = b2; m = m2; v = v2; al = a2; be = be2; }
    else { g = g3; b = b3; m = m3; v = v3; al = a3; be = be3; }
    float a = g[e] / sqrtf(v[e] + 1e-5f);
    al[e] = a;
    be[e] = b[e] - m[e] * a;
  }
}

// ---------------- i8 MFMA layer: C = A x W^T ------------------------------
// Block 256(m) x 256(n) x BK=128 bytes. LDS: 2 buffers x (A 32KB | B 32KB),
// rows of 128B, 16B chunks XOR-(row&7) swizzled at the global source
// (linear global_load_lds dest, rule 21).
// Per K-tile: 4 phases (phase q = m-tile q of the wave: 2nt x 4ks = 8 MFMA
// of 32x32x32), 2 barriers/phase, prefetch of next tile issued in phases
// 0-1, per-wave vmcnt(0) at phase-3 end. Exactly the R5 sync shape.
// FINAL: dot with sign(wout) rows, atomicAdd exact-integer partials (f32).
template <int K, bool FINAL>
__global__ __launch_bounds__(512, 1) void layer_mfma(
    const char* __restrict__ A, const char* __restrict__ W,
    const float* __restrict__ alpha, const float* __restrict__ beta,
    char* __restrict__ O, const float* __restrict__ wout,
    float* __restrict__ out) {
  constexpr int N = Hid;
  constexpr int NT = K / 128;  // K-tiles
  __shared__ __align__(16) char lds[131072];

  const int tid = threadIdx.x;
  const int wave = tid >> 6, lane = tid & 63;

  // R5 dispatch swizzle: XCD x (= id&7) owns mp [x*8, x*8+8), np outermost.
  const int id = blockIdx.x;
  const int mp = (id & 7) * 8 + ((id >> 3) & 7);
  const int np = id >> 6;
  const int m0 = mp * 256, n0 = np * 256;

  // staging: 4096 chunks of 16B per K-tile (A chunks 0..2047, B 2048..4095).
  // wave w, issue i covers chunks [w*512 + i*64, +64) -> 8 ld16 per lane.
  const char* gp[8];
  int lo[8];
#pragma unroll
  for (int i = 0; i < 8; ++i) {
    int run = wave * 512 + i * 64;            // lane-0 chunk id (uniform)
    bool isA = run < 2048;
    int crun = isA ? run : run - 2048;
    int c = crun + lane;                      // this lane's chunk
    int row = c >> 3;
    int kc = (c & 7) ^ (row & 7);             // pre-swizzled source chunk
    gp[i] = (isA ? A + (size_t)(m0 + row) * K
                 : W + (size_t)(n0 + row) * K) + kc * 16;
    lo[i] = (isA ? 0 : 32768) + crun * 16;    // wave-uniform LDS base
  }

  // ---- fragment-read offsets (32x32x32 layout) ----
  const int l31 = lane & 31, lk2 = lane >> 5;
  const int wm = wave >> 2, wn = wave & 3;
  int xsk[4];
#pragma unroll
  for (int ks = 0; ks < 4; ++ks)
    xsk[ks] = ((ks * 2 + lk2) ^ (l31 & 7)) * 16;  // phys chunk byte offset
  const int abase = (wm * 128 + l31) * 128;             // + q*4096 + xsk
  const int bbase = 32768 + (wn * 64 + l31) * 128;      // + nt*4096 + xsk

  i32x16 acc[4][2] = {};

  // prologue: stage K-tile 0 into buf0, full drain once.
#pragma unroll
  for (int i = 0; i < 8; ++i) {
    ld16(gp[i], lds + lo[i]);
    gp[i] += 128;
  }
  asm volatile("s_waitcnt vmcnt(0)" ::: "memory");
  __builtin_amdgcn_s_barrier();

#pragma unroll 1
  for (int t = 0; t < NT; ++t) {
    const int rb = (t & 1) << 16;   // read buffer
    const int wb = rb ^ 65536;      // write (prefetch) buffer
    const bool pf = (t + 1 < NT);

    // B fragments for the whole K-tile (8 ds_read_b128), read once.
    i32x4 bF[2][4];
#pragma unroll
    for (int nt = 0; nt < 2; ++nt)
#pragma unroll
      for (int ks = 0; ks < 4; ++ks)
        bF[nt][ks] = *(const i32x4*)(lds + rb + bbase + nt * 4096 + xsk[ks]);

#pragma unroll
    for (int q = 0; q < 4; ++q) {
      // m-tile q A fragments (4 ds_read_b128)
      i32x4 aF[4];
#pragma unroll
      for (int ks = 0; ks < 4; ++ks)
        aF[ks] = *(const i32x4*)(lds + rb + abase + q * 4096 + xsk[ks]);
      // issue next-tile staging early (phases 0-1), into the other buffer
      if (pf && q < 2) {
#pragma unroll
        for (int i = 0; i < 4; ++i) {
          int j = q * 4 + i;
          ld16(gp[j], lds + wb + lo[j]);
          gp[j] += 128;
        }
      }
      __builtin_amdgcn_s_barrier();
      asm volatile("s_waitcnt lgkmcnt(0)" ::: "memory");
      __builtin_amdgcn_s_setprio(1);
#pragma unroll
      for (int ks = 0; ks < 4; ++ks)
#pragma unroll
        for (int nt = 0; nt < 2; ++nt)
          acc[q][nt] = __builtin_amdgcn_mfma_i32_32x32x32_i8(
              aF[ks], bF[nt][ks], acc[q][nt], 0, 0, 0);
      __builtin_amdgcn_s_setprio(0);
      // tile end: drain own staging loads (issued >=2 phases ago), then the
      // barrier publishes the swapped buffer.
      if (q == 3) asm volatile("s_waitcnt vmcnt(0)" ::: "memory");
      __builtin_amdgcn_s_barrier();
    }
  }

  float al[2], be[2];
#pragma unroll
  for (int nt = 0; nt < 2; ++nt) {
    int n = n0 + wn * 64 + nt * 32 + l31;
    al[nt] = alpha[n];
    be[nt] = beta[n];
  }

  if (!FINAL) {
#pragma unroll
    for (int mt = 0; mt < 4; ++mt)
#pragma unroll
      for (int r = 0; r < 16; ++r) {
        // C/D row = (reg&3) + 8*(reg>>2) + 4*(lane>>5)
        int m = m0 + wm * 128 + mt * 32 + (r & 3) + 8 * (r >> 2) + 4 * lk2;
        char* orow = O + (size_t)m * N;
#pragma unroll
        for (int nt = 0; nt < 2; ++nt) {
          float c = (float)acc[mt][nt][r];
          orow[n0 + wn * 64 + nt * 32 + l31] =
              (fmaf(al[nt], c, be[nt]) >= 0.0f) ? 1 : -1;
        }
      }
  } else {
    int ws0[2], ws1[2];
#pragma unroll
    for (int nt = 0; nt < 2; ++nt) {
      int n = n0 + wn * 64 + nt * 32 + l31;
      ws0[nt] = (wout[n] >= 0.0f) ? 1 : -1;
      ws1[nt] = (wout[2048 + n] >= 0.0f) ? 1 : -1;
    }
#pragma unroll
    for (int mt = 0; mt < 4; ++mt)
#pragma unroll
      for (int r = 0; r < 16; ++r) {
        int m = m0 + wm * 128 + mt * 32 + (r & 3) + 8 * (r >> 2) + 4 * lk2;
        int p0 = 0, p1 = 0;
#pragma unroll
        for (int nt = 0; nt < 2; ++nt) {
          float c = (float)acc[mt][nt][r];
          int a = (fmaf(al[nt], c, be[nt]) >= 0.0f) ? 1 : -1;
          p0 += a * ws0[nt];
          p1 += a * ws1[nt];
        }
        // reduce over n within each 32-lane half (lanes hold l31 = n-col);
        // lane>>5 halves hold DIFFERENT m rows -> reduce width 32.
#pragma unroll
        for (int off = 1; off <= 16; off <<= 1) {
          p0 += __shfl_xor(p0, off, 32);
          p1 += __shfl_xor(p1, off, 32);
        }
        if (l31 == 0) {
          atomicAdd(&out[m * 2 + 0], (float)p0);
          atomicAdd(&out[m * 2 + 1], (float)p1);
        }
      }
  }
}

extern "C" void kernel_launch(void* const* d_in, const int* in_sizes, int n_in,
                              void* d_out, int out_size, void* d_ws, size_t ws_size,
                              hipStream_t stream) {
  const float* x    = (const float*)d_in[0];
  const float* w1   = (const float*)d_in[1];
  const float* g1   = (const float*)d_in[2];
  const float* b1   = (const float*)d_in[3];
  const float* m1   = (const float*)d_in[4];
  const float* v1   = (const float*)d_in[5];
  const float* w2   = (const float*)d_in[6];
  const float* g2   = (const float*)d_in[7];
  const float* b2   = (const float*)d_in[8];
  const float* m2   = (const float*)d_in[9];
  const float* v2   = (const float*)d_in[10];
  const float* w3   = (const float*)d_in[11];
  const float* g3   = (const float*)d_in[12];
  const float* b3   = (const float*)d_in[13];
  const float* m3   = (const float*)d_in[14];
  const float* v3   = (const float*)d_in[15];
  const float* wout = (const float*)d_in[16];
  float* out = (float*)d_out;

  char* base = (char*)d_ws;
  size_t off = 0;
  auto take = [&](size_t bytes) -> char* {
    char* p = base + off;
    off += (bytes + 255) & ~(size_t)255;
    return p;
  };
  char* A0  = take((size_t)Bsz * Din);
  char* Aa  = take((size_t)Bsz * Hid);
  char* Ab  = take((size_t)Bsz * Hid);
  char* W1s = take((size_t)Hid * Din);
  char* W2s = take((size_t)Hid * Hid);
  char* W3s = take((size_t)Hid * Hid);
  float* a1  = (float*)take(Hid * 4);
  float* be1 = (float*)take(Hid * 4);
  float* a2  = (float*)take(Hid * 4);
  float* be2 = (float*)take(Hid * 4);
  float* a3  = (float*)take(Hid * 4);
  float* be3 = (float*)take(Hid * 4);

  hipMemsetAsync(d_out, 0, (size_t)out_size * sizeof(float), stream);

  prep_kernel<<<26648, 256, 0, stream>>>(
      x, w1, w2, w3,
      g1, b1, m1, v1, g2, b2, m2, v2, g3, b3, m3, v3,
      A0, W1s, W2s, W3s, a1, be1, a2, be2, a3, be3);

  // grid 512: (16384/256) m-panels x (2048/256) n-panels, XCD-swizzled
  layer_mfma<Din, false><<<512, 512, 0, stream>>>(A0, W1s, a1, be1, Aa,
                                                  nullptr, nullptr);
  layer_mfma<Hid, false><<<512, 512, 0, stream>>>(Aa, W2s, a2, be2, Ab,
                                                  nullptr, nullptr);
  layer_mfma<Hid, true><<<512, 512, 0, stream>>>(Ab, W3s, a3, be3, nullptr,
                                                 wout, out);
}

// Round 6
// 284.698 us; speedup vs baseline: 1.2272x; 1.2272x over previous
//
#include <hip/hip_runtime.h>
#include <cstdint>
#include <cmath>

// Binarized MLP via MX-fp4 scale-MFMA: 16384x1024 -> 2048 -> 2048 -> 2048 -> 2.
// R10 = R5's exact verified schedule (256x256 tile, 8 waves 2m x 4n,
// double-buffered 128KB LDS, 4 phases/K-tile, 2 barriers/phase, prefetch in
// phases 0-1, vmcnt(0) at tile end) with operands in fp4 e2m1 (+1=0x2,
// -1=0xA) via mfma_scale_f32_32x32x64_f8f6f4 FMT=fp4, scales=1.0
// (E8M0 127). Exact: products are +-1, f32 accum |sum|<=2048.
// fp4 ceiling 9099 TOPS = 2.07x i8; bytes/elem halve -> staging geometry at
// K-tile=256 elems is 128B rows, byte-identical to R5 (4096 x 16B chunks,
// XOR-(row&7) pre-swizzled source, 0-conflict staging). Fragment = one 16B
// chunk (s*2+(lane>>5), R9-verified xsk family); C/D = R9-verified 32x32
// layout. Epilogue packs output nibbles (pairwise shfl_xor).

typedef int i32x4 __attribute__((ext_vector_type(4)));
typedef int i32x8 __attribute__((ext_vector_type(8)));
typedef float f32x16 __attribute__((ext_vector_type(16)));

static constexpr int Bsz = 16384;
static constexpr int Din = 1024;
static constexpr int Hid = 2048;

__device__ __forceinline__ void ld16(const void* g, void* l) {
  __builtin_amdgcn_global_load_lds(
      (const __attribute__((address_space(1))) void*)g,
      (__attribute__((address_space(3))) void*)l, 16, 0, 0);
}

// ---------------- fused prep: sign-quantize to packed fp4 + BN folds -------
// Each thread packs 8 floats -> 8 fp4 nibbles (u32). Elem j -> bits[4j+3:4j]
// (byte j>>1, lo nibble = even elem).
// blocks [0,8192): x (thr 0.5)   [8192,9216): w1   [9216,11264): w2
// [11264,13312): w3              [13312,13336): bnprep
__global__ void prep_kernel(
    const float* __restrict__ x, const float* __restrict__ w1,
    const float* __restrict__ w2, const float* __restrict__ w3,
    const float* __restrict__ g1, const float* __restrict__ b1,
    const float* __restrict__ m1, const float* __restrict__ v1,
    const float* __restrict__ g2, const float* __restrict__ b2,
    const float* __restrict__ m2, const float* __restrict__ v2,
    const float* __restrict__ g3, const float* __restrict__ b3,
    const float* __restrict__ m3, const float* __restrict__ v3,
    unsigned* __restrict__ A0, unsigned* __restrict__ W1s,
    unsigned* __restrict__ W2s, unsigned* __restrict__ W3s,
    float* __restrict__ a1, float* __restrict__ be1,
    float* __restrict__ a2, float* __restrict__ be2,
    float* __restrict__ a3, float* __restrict__ be3) {
  constexpr int BX = 8192, BW1 = 1024, BW2 = 2048, BW3 = 2048;
  const int blk = blockIdx.x;
  if (blk < BX + BW1 + BW2 + BW3) {
    const float* s;
    unsigned* d;
    float thr = 0.0f;
    int rb;
    if (blk < BX) {
      s = x; d = A0; thr = 0.5f; rb = 0;
    } else if (blk < BX + BW1) {
      s = w1; d = W1s; rb = BX;
    } else if (blk < BX + BW1 + BW2) {
      s = w2; d = W2s; rb = BX + BW1;
    } else {
      s = w3; d = W3s; rb = BX + BW1 + BW2;
    }
    int i = (blk - rb) * 256 + threadIdx.x;
    float4 v0 = ((const float4*)s)[2 * i];
    float4 v1 = ((const float4*)s)[2 * i + 1];
    float e[8] = {v0.x, v0.y, v0.z, v0.w, v1.x, v1.y, v1.z, v1.w};
    unsigned w = 0;
#pragma unroll
    for (int j = 0; j < 8; ++j)
      w |= ((e[j] >= thr) ? 0x2u : 0xAu) << (4 * j);
    d[i] = w;
  } else {
    int t = (blk - (BX + BW1 + BW2 + BW3)) * 256 + threadIdx.x;  // 0..6143
    int l = t >> 11, e = t & 2047;
    const float *g, *b, *m, *v;
    float *al, *be;
    if (l == 0) { g = g1; b = b1; m = m1; v = v1; al = a1; be = be1; }
    else if (l == 1) { g = g2; b = b2; m = m2; v = v2; al = a2; be = be2; }
    else { g = g3; b = b3; m = m3; v = v3; al = a3; be = be3; }
    float a = g[e] / sqrtf(v[e] + 1e-5f);
    al[e] = a;
    be[e] = b[e] - m[e] * a;
  }
}

// ---------------- fp4 MFMA layer: C = A x W^T -----------------------------
// K = k-elements (template). Rows packed fp4: KB=K/2 bytes/row.
// K-tile = 256 elems = 128B rows; LDS 2 buffers x (A 32KB | B 32KB).
// Per K-tile: 4 phases (phase q = m-tile q: 2nt x 4ks = 8 MFMA of
// 32x32x64 fp4), 2 barriers/phase, prefetch in phases 0-1, vmcnt(0) at
// phase-3 end: the R5-verified sync shape.
// FINAL: dot with sign(wout) rows, atomicAdd exact-integer partials (f32).
template <int K, bool FINAL>
__global__ __launch_bounds__(512, 1) void layer_mfma(
    const char* __restrict__ A, const char* __restrict__ W,
    const float* __restrict__ alpha, const float* __restrict__ beta,
    char* __restrict__ O, const float* __restrict__ wout,
    float* __restrict__ out) {
  constexpr int N = Hid;
  constexpr int KB = K / 2;    // bytes per packed row
  constexpr int NT = KB / 128; // K-tiles of 128B (=256 elems)
  __shared__ __align__(16) char lds[131072];

  const int tid = threadIdx.x;
  const int wave = tid >> 6, lane = tid & 63;

  // R5 dispatch swizzle: XCD x (= id&7) owns mp [x*8, x*8+8), np outermost.
  const int id = blockIdx.x;
  const int mp = (id & 7) * 8 + ((id >> 3) & 7);
  const int np = id >> 6;
  const int m0 = mp * 256, n0 = np * 256;

  // staging: 4096 chunks of 16B per K-tile (A 0..2047, B 2048..4095);
  // wave w, issue i covers chunks [w*512 + i*64, +64) -> 8 ld16 per lane.
  const char* gp[8];
  int lo[8];
#pragma unroll
  for (int i = 0; i < 8; ++i) {
    int run = wave * 512 + i * 64;
    bool isA = run < 2048;
    int crun = isA ? run : run - 2048;
    int c = crun + lane;
    int row = c >> 3;
    int kc = (c & 7) ^ (row & 7);             // pre-swizzled source chunk
    gp[i] = (isA ? A + (size_t)(m0 + row) * KB
                 : W + (size_t)(n0 + row) * KB) + kc * 16;
    lo[i] = (isA ? 0 : 32768) + crun * 16;
  }

  // ---- fragment-read offsets (32x32x64 fp4: lane k = (l>>5)*32+nibble) ----
  const int l31 = lane & 31, lk2 = lane >> 5;
  const int wm = wave >> 2, wn = wave & 3;
  int xsk[4];
#pragma unroll
  for (int s = 0; s < 4; ++s)
    xsk[s] = ((s * 2 + lk2) ^ (l31 & 7)) * 16;  // phys 16B chunk offset
  const int abase = wm * 16384 + l31 * 128;               // + q*4096 + xsk
  const int bbase = 32768 + wn * 8192 + l31 * 128;        // + nt*4096 + xsk

  // fp4 uses only the low 4 regs of the 8-reg operand; zero-init high once.
  i32x8 a8[4] = {};
  i32x8 b8[2][4] = {};
  f32x16 acc[4][2] = {};

  // prologue: stage K-tile 0 into buf0, full drain once.
#pragma unroll
  for (int i = 0; i < 8; ++i) {
    ld16(gp[i], lds + lo[i]);
    gp[i] += 128;
  }
  asm volatile("s_waitcnt vmcnt(0)" ::: "memory");
  __builtin_amdgcn_s_barrier();

#pragma unroll 1
  for (int t = 0; t < NT; ++t) {
    const int rb = (t & 1) << 16;   // read buffer
    const int wb = rb ^ 65536;      // write (prefetch) buffer
    const bool pf = (t + 1 < NT);

    // B fragments for the whole K-tile (8 ds_read_b128 into low halves).
#pragma unroll
    for (int nt = 0; nt < 2; ++nt)
#pragma unroll
      for (int s = 0; s < 4; ++s)
        *(i32x4*)&b8[nt][s] =
            *(const i32x4*)(lds + rb + bbase + nt * 4096 + xsk[s]);

#pragma unroll
    for (int q = 0; q < 4; ++q) {
      // m-tile q A fragments (4 ds_read_b128 into low halves)
#pragma unroll
      for (int s = 0; s < 4; ++s)
        *(i32x4*)&a8[s] =
            *(const i32x4*)(lds + rb + abase + q * 4096 + xsk[s]);
      // issue next-tile staging early (phases 0-1), into the other buffer
      if (pf && q < 2) {
#pragma unroll
        for (int i = 0; i < 4; ++i) {
          int j = q * 4 + i;
          ld16(gp[j], lds + wb + lo[j]);
          gp[j] += 128;
        }
      }
      __builtin_amdgcn_s_barrier();
      asm volatile("s_waitcnt lgkmcnt(0)" ::: "memory");
      __builtin_amdgcn_s_setprio(1);
#pragma unroll
      for (int s = 0; s < 4; ++s)
#pragma unroll
        for (int nt = 0; nt < 2; ++nt)
          acc[q][nt] = __builtin_amdgcn_mfma_scale_f32_32x32x64_f8f6f4(
              a8[s], b8[nt][s], acc[q][nt], 4, 4,  // FMT A=fp4, B=fp4
              0, 0x7F7F7F7F, 0, 0x7F7F7F7F);       // scales = 1.0 (E8M0 127)
      __builtin_amdgcn_s_setprio(0);
      if (q == 3) asm volatile("s_waitcnt vmcnt(0)" ::: "memory");
      __builtin_amdgcn_s_barrier();
    }
  }

  float al[2], be[2];
#pragma unroll
  for (int nt = 0; nt < 2; ++nt) {
    int n = n0 + wn * 64 + nt * 32 + l31;
    al[nt] = alpha[n];
    be[nt] = beta[n];
  }

  if (!FINAL) {
    // pack output fp4 nibbles: even lane stores the nt=0 byte (cols n,n+1),
    // odd lane the nt=1 byte. Row length N/2 bytes.
    const int bb0 = (n0 + wn * 64) >> 1;
#pragma unroll
    for (int mt = 0; mt < 4; ++mt)
#pragma unroll
      for (int r = 0; r < 16; ++r) {
        int m = m0 + wm * 128 + mt * 32 + (r & 3) + 8 * (r >> 2) + 4 * lk2;
        unsigned nib0 =
            (fmaf(al[0], acc[mt][0][r], be[0]) >= 0.0f) ? 0x2u : 0xAu;
        unsigned nib1 =
            (fmaf(al[1], acc[mt][1][r], be[1]) >= 0.0f) ? 0x2u : 0xAu;
        unsigned o0 = __shfl_xor(nib0, 1, 64);
        unsigned o1 = __shfl_xor(nib1, 1, 64);
        char* orow = O + (size_t)m * (N / 2);
        if ((lane & 1) == 0)
          orow[bb0 + (l31 >> 1)] = (char)(nib0 | (o0 << 4));
        else
          orow[bb0 + 16 + (l31 >> 1)] = (char)(o1 | (nib1 << 4));
      }
  } else {
    int ws0[2], ws1[2];
#pragma unroll
    for (int nt = 0; nt < 2; ++nt) {
      int n = n0 + wn * 64 + nt * 32 + l31;
      ws0[nt] = (wout[n] >= 0.0f) ? 1 : -1;
      ws1[nt] = (wout[2048 + n] >= 0.0f) ? 1 : -1;
    }
#pragma unroll
    for (int mt = 0; mt < 4; ++mt)
#pragma unroll
      for (int r = 0; r < 16; ++r) {
        int m = m0 + wm * 128 + mt * 32 + (r & 3) + 8 * (r >> 2) + 4 * lk2;
        int p0 = 0, p1 = 0;
#pragma unroll
        for (int nt = 0; nt < 2; ++nt) {
          int a = (fmaf(al[nt], acc[mt][nt][r], be[nt]) >= 0.0f) ? 1 : -1;
          p0 += a * ws0[nt];
          p1 += a * ws1[nt];
        }
        // reduce over n within each 32-lane half (l31 = n-col; lane>>5
        // halves hold different m rows) -> width 32.
#pragma unroll
        for (int off = 1; off <= 16; off <<= 1) {
          p0 += __shfl_xor(p0, off, 32);
          p1 += __shfl_xor(p1, off, 32);
        }
        if (l31 == 0) {
          atomicAdd(&out[m * 2 + 0], (float)p0);
          atomicAdd(&out[m * 2 + 1], (float)p1);
        }
      }
  }
}

extern "C" void kernel_launch(void* const* d_in, const int* in_sizes, int n_in,
                              void* d_out, int out_size, void* d_ws, size_t ws_size,
                              hipStream_t stream) {
  const float* x    = (const float*)d_in[0];
  const float* w1   = (const float*)d_in[1];
  const float* g1   = (const float*)d_in[2];
  const float* b1   = (const float*)d_in[3];
  const float* m1   = (const float*)d_in[4];
  const float* v1   = (const float*)d_in[5];
  const float* w2   = (const float*)d_in[6];
  const float* g2   = (const float*)d_in[7];
  const float* b2   = (const float*)d_in[8];
  const float* m2   = (const float*)d_in[9];
  const float* v2   = (const float*)d_in[10];
  const float* w3   = (const float*)d_in[11];
  const float* g3   = (const float*)d_in[12];
  const float* b3   = (const float*)d_in[13];
  const float* m3   = (const float*)d_in[14];
  const float* v3   = (const float*)d_in[15];
  const float* wout = (const float*)d_in[16];
  float* out = (float*)d_out;

  char* base = (char*)d_ws;
  size_t off = 0;
  auto take = [&](size_t bytes) -> char* {
    char* p = base + off;
    off += (bytes + 255) & ~(size_t)255;
    return p;
  };
  char* A0  = take((size_t)Bsz * Din / 2);
  char* Aa  = take((size_t)Bsz * Hid / 2);
  char* Ab  = take((size_t)Bsz * Hid / 2);
  char* W1s = take((size_t)Hid * Din / 2);
  char* W2s = take((size_t)Hid * Hid / 2);
  char* W3s = take((size_t)Hid * Hid / 2);
  float* a1  = (float*)take(Hid * 4);
  float* be1 = (float*)take(Hid * 4);
  float* a2  = (float*)take(Hid * 4);
  float* be2 = (float*)take(Hid * 4);
  float* a3  = (float*)take(Hid * 4);
  float* be3 = (float*)take(Hid * 4);

  hipMemsetAsync(d_out, 0, (size_t)out_size * sizeof(float), stream);

  prep_kernel<<<13336, 256, 0, stream>>>(
      x, w1, w2, w3,
      g1, b1, m1, v1, g2, b2, m2, v2, g3, b3, m3, v3,
      (unsigned*)A0, (unsigned*)W1s, (unsigned*)W2s, (unsigned*)W3s,
      a1, be1, a2, be2, a3, be3);

  // grid 512: (16384/256) m-panels x (2048/256) n-panels, XCD-swizzled
  layer_mfma<Din, false><<<512, 512, 0, stream>>>(A0, W1s, a1, be1, Aa,
                                                  nullptr, nullptr);
  layer_mfma<Hid, false><<<512, 512, 0, stream>>>(Aa, W2s, a2, be2, Ab,
                                                  nullptr, nullptr);
  layer_mfma<Hid, true><<<512, 512, 0, stream>>>(Ab, W3s, a3, be3, nullptr,
                                                 wout, out);
}

// Round 7
// 263.874 us; speedup vs baseline: 1.3240x; 1.0789x over previous
//
#include <hip/hip_runtime.h>
#include <cstdint>
#include <cmath>

// Binarized MLP via MX-fp4 scale-MFMA: 16384x1024 -> 2048 -> 2048 -> 2048 -> 2.
// R11 = R4's high-occupancy structure (256x128 tile, 48KB single-buffered
// LDS, 8 waves 4m x 2n, plain __syncthreads loop, 2+ blocks/CU co-resident
// for cross-block latency hiding; grid 1024, XCD swizzle) with fp4 e2m1
// operands (+1=0x2, -1=0xA) and mfma_scale_f32_16x16x128_f8f6f4 (FMT=4,
// scale=E8M0 127 -> 1.0). Exact: products +-1, f32 accum |sum|<=2048.
// 16x16 family -> R5-verified zero-conflict LDS reads (chunk (s*4+lk)^(lr&7))
// and R5-verified C/D layout (col=lane&15, row=(lane>>4)*4+reg).
// R10's evidence: 1-block/CU lockstep pipeline is latency-bound (70% idle);
// R4's co-resident blocks ran staging at 7.3 TB/s aggregate. fp4 halves the
// bytes R4 had to stage.

typedef int i32x4 __attribute__((ext_vector_type(4)));
typedef int i32x8 __attribute__((ext_vector_type(8)));
typedef float f32x4 __attribute__((ext_vector_type(4)));

static constexpr int Bsz = 16384;
static constexpr int Din = 1024;
static constexpr int Hid = 2048;

__device__ __forceinline__ void ld16(const void* g, void* l) {
  __builtin_amdgcn_global_load_lds(
      (const __attribute__((address_space(1))) void*)g,
      (__attribute__((address_space(3))) void*)l, 16, 0, 0);
}

// ---------------- fused prep: sign-quantize to packed fp4 + BN folds -------
// Each thread packs 8 floats -> 8 fp4 nibbles (u32). Elem j -> bits[4j+3:4j]
// (byte j>>1, lo nibble = even elem).
// blocks [0,8192): x (thr 0.5)   [8192,9216): w1   [9216,11264): w2
// [11264,13312): w3              [13312,13336): bnprep
__global__ void prep_kernel(
    const float* __restrict__ x, const float* __restrict__ w1,
    const float* __restrict__ w2, const float* __restrict__ w3,
    const float* __restrict__ g1, const float* __restrict__ b1,
    const float* __restrict__ m1, const float* __restrict__ v1,
    const float* __restrict__ g2, const float* __restrict__ b2,
    const float* __restrict__ m2, const float* __restrict__ v2,
    const float* __restrict__ g3, const float* __restrict__ b3,
    const float* __restrict__ m3, const float* __restrict__ v3,
    unsigned* __restrict__ A0, unsigned* __restrict__ W1s,
    unsigned* __restrict__ W2s, unsigned* __restrict__ W3s,
    float* __restrict__ a1, float* __restrict__ be1,
    float* __restrict__ a2, float* __restrict__ be2,
    float* __restrict__ a3, float* __restrict__ be3) {
  constexpr int BX = 8192, BW1 = 1024, BW2 = 2048, BW3 = 2048;
  const int blk = blockIdx.x;
  if (blk < BX + BW1 + BW2 + BW3) {
    const float* s;
    unsigned* d;
    float thr = 0.0f;
    int rb;
    if (blk < BX) {
      s = x; d = A0; thr = 0.5f; rb = 0;
    } else if (blk < BX + BW1) {
      s = w1; d = W1s; rb = BX;
    } else if (blk < BX + BW1 + BW2) {
      s = w2; d = W2s; rb = BX + BW1;
    } else {
      s = w3; d = W3s; rb = BX + BW1 + BW2;
    }
    int i = (blk - rb) * 256 + threadIdx.x;
    float4 v0 = ((const float4*)s)[2 * i];
    float4 v1 = ((const float4*)s)[2 * i + 1];
    float e[8] = {v0.x, v0.y, v0.z, v0.w, v1.x, v1.y, v1.z, v1.w};
    unsigned w = 0;
#pragma unroll
    for (int j = 0; j < 8; ++j)
      w |= ((e[j] >= thr) ? 0x2u : 0xAu) << (4 * j);
    d[i] = w;
  } else {
    int t = (blk - (BX + BW1 + BW2 + BW3)) * 256 + threadIdx.x;  // 0..6143
    int l = t >> 11, e = t & 2047;
    const float *g, *b, *m, *v;
    float *al, *be;
    if (l == 0) { g = g1; b = b1; m = m1; v = v1; al = a1; be = be1; }
    else if (l == 1) { g = g2; b = b2; m = m2; v = v2; al = a2; be = be2; }
    else { g = g3; b = b3; m = m3; v = v3; al = a3; be = be3; }
    float a = g[e] / sqrtf(v[e] + 1e-5f);
    al[e] = a;
    be[e] = b[e] - m[e] * a;
  }
}

// ---------------- fp4 MFMA layer: C = A x W^T -----------------------------
// Block 256(m) x 128(n) x K-tile 128B (=256 elems). 8 waves as 4(m) x 2(n);
// wave tile 64x64 = 4x4 mfma 16x16 frags. LDS single buffer 48KB:
// A @0 (256 rows x 128B), B @32768 (128 rows x 128B). 16B chunks
// XOR-(row&7) swizzled at the global source (linear DMA dest, rule 21).
// Per K-tile: stage 48KB (6 ld16/wave) -> __syncthreads (drains DMA) ->
// 2 k-slices x (4 bF + 4x(aF + 4 MFMA)) -> __syncthreads. R4's exact shape.
// FINAL: dot with sign(wout) rows, atomicAdd exact-integer partials (f32).
template <int K, bool FINAL>
__global__ __launch_bounds__(512, 4) void layer_mfma(
    const char* __restrict__ A, const char* __restrict__ W,
    const float* __restrict__ alpha, const float* __restrict__ beta,
    char* __restrict__ O, const float* __restrict__ wout,
    float* __restrict__ out) {
  constexpr int N = Hid;
  constexpr int KB = K / 2;    // bytes per packed row
  constexpr int NT = KB / 128; // K-tiles of 128B (=256 elems)
  __shared__ __align__(16) char lds[49152];  // A 32KB | B 16KB

  const int tid = threadIdx.x;
  const int wave = tid >> 6, lane = tid & 63;

  // R4 swizzle: XCD x (= id&7) owns mp [x*8, x*8+8), np outermost.
  const int id = blockIdx.x;
  const int mp = (id & 7) * 8 + ((id >> 3) & 7);
  const int np = id >> 6;
  const int m0 = mp * 256, n0 = np * 128;

  // staging: 48 chunks of 1KB (A: 0..31 = 256 rows x 128B, B: 32..47 =
  // 128 rows x 128B); wave w covers chunks [w*6, w*6+6).
  const char* gp[6];
  char* lp[6];
#pragma unroll
  for (int ci = 0; ci < 6; ++ci) {
    int c = wave * 6 + ci;
    bool isA = c < 32;
    int cc = isA ? c : c - 32;
    int row = cc * 8 + (lane >> 3);
    int kc = (lane & 7) ^ (row & 7);  // pre-swizzled source chunk
    gp[ci] = (isA ? A + (size_t)(m0 + row) * KB
                  : W + (size_t)(n0 + row) * KB) + kc * 16;
    lp[ci] = &lds[(isA ? 0 : 32768) + cc * 1024];
  }

  // fragment reads: R5-verified zero-conflict pattern.
  const int lr = lane & 15, lk = lane >> 4;
  const int wm = wave >> 1, wn = wave & 1;
  const int xs0 = ((0 + lk) ^ (lr & 7)) * 16;  // k-slice 0 chunk slot
  const int xs1 = ((4 + lk) ^ (lr & 7)) * 16;  // k-slice 1 chunk slot
  const int abase = (wm * 64 + lr) * 128;             // + mt*2048 + xs
  const int bbase = 32768 + (wn * 64 + lr) * 128;     // + nt*2048 + xs

  f32x4 acc[4][4] = {};
  i32x8 aop = {};      // fp4 uses low 4 regs; high half stays zero
  i32x8 bop[4] = {};

#pragma unroll 1
  for (int t = 0; t < NT; ++t) {
#pragma unroll
    for (int ci = 0; ci < 6; ++ci) {
      ld16(gp[ci], lp[ci]);
      gp[ci] += 128;
    }
    __syncthreads();  // drains DMA (vmcnt0 before barrier)
#pragma unroll
    for (int s = 0; s < 2; ++s) {
      const int xs = s ? xs1 : xs0;
#pragma unroll
      for (int nt = 0; nt < 4; ++nt)
        *(i32x4*)&bop[nt] = *(const i32x4*)(lds + bbase + nt * 2048 + xs);
#pragma unroll
      for (int mt = 0; mt < 4; ++mt) {
        *(i32x4*)&aop = *(const i32x4*)(lds + abase + mt * 2048 + xs);
#pragma unroll
        for (int nt = 0; nt < 4; ++nt)
          acc[mt][nt] = __builtin_amdgcn_mfma_scale_f32_16x16x128_f8f6f4(
              aop, bop[nt], acc[mt][nt], 4, 4,   // FMT A=fp4, B=fp4
              0, 0x7F7F7F7F, 0, 0x7F7F7F7F);     // scales = 1.0 (E8M0 127)
      }
    }
    __syncthreads();  // protect single buffer before next tile's DMA
  }

  float al[4], be[4];
#pragma unroll
  for (int nt = 0; nt < 4; ++nt) {
    int n = n0 + wn * 64 + nt * 16 + lr;
    al[nt] = alpha[n];
    be[nt] = beta[n];
  }

  if (!FINAL) {
    // pack output fp4 nibbles: lane pairs (lr even/odd) share one byte;
    // even lane stores lo|hi after grabbing partner's nibble via shfl_xor 1.
    const int bb0 = (n0 + wn * 64) >> 1;
#pragma unroll
    for (int mt = 0; mt < 4; ++mt)
#pragma unroll
      for (int r = 0; r < 4; ++r) {
        int m = m0 + wm * 64 + mt * 16 + lk * 4 + r;  // C/D row=(lane>>4)*4+reg
        char* orow = O + (size_t)m * (N / 2);
#pragma unroll
        for (int nt = 0; nt < 4; ++nt) {
          unsigned nib =
              (fmaf(al[nt], acc[mt][nt][r], be[nt]) >= 0.0f) ? 0x2u : 0xAu;
          unsigned pn = __shfl_xor(nib, 1, 64);
          if ((lane & 1) == 0)
            orow[bb0 + ((nt * 16 + lr) >> 1)] = (char)(nib | (pn << 4));
        }
      }
  } else {
    int ws0[4], ws1[4];
#pragma unroll
    for (int nt = 0; nt < 4; ++nt) {
      int n = n0 + wn * 64 + nt * 16 + lr;
      ws0[nt] = (wout[n] >= 0.0f) ? 1 : -1;
      ws1[nt] = (wout[2048 + n] >= 0.0f) ? 1 : -1;
    }
#pragma unroll
    for (int mt = 0; mt < 4; ++mt)
#pragma unroll
      for (int r = 0; r < 4; ++r) {
        int m = m0 + wm * 64 + mt * 16 + lk * 4 + r;
        int p0 = 0, p1 = 0;
#pragma unroll
        for (int nt = 0; nt < 4; ++nt) {
          int a = (fmaf(al[nt], acc[mt][nt][r], be[nt]) >= 0.0f) ? 1 : -1;
          p0 += a * ws0[nt];
          p1 += a * ws1[nt];
        }
        // reduce across lr (lane bits 0..3)
#pragma unroll
        for (int off = 1; off <= 8; off <<= 1) {
          p0 += __shfl_xor(p0, off, 64);
          p1 += __shfl_xor(p1, off, 64);
        }
        if (lr == 0) {
          atomicAdd(&out[m * 2 + 0], (float)p0);
          atomicAdd(&out[m * 2 + 1], (float)p1);
        }
      }
  }
}

extern "C" void kernel_launch(void* const* d_in, const int* in_sizes, int n_in,
                              void* d_out, int out_size, void* d_ws, size_t ws_size,
                              hipStream_t stream) {
  const float* x    = (const float*)d_in[0];
  const float* w1   = (const float*)d_in[1];
  const float* g1   = (const float*)d_in[2];
  const float* b1   = (const float*)d_in[3];
  const float* m1   = (const float*)d_in[4];
  const float* v1   = (const float*)d_in[5];
  const float* w2   = (const float*)d_in[6];
  const float* g2   = (const float*)d_in[7];
  const float* b2   = (const float*)d_in[8];
  const float* m2   = (const float*)d_in[9];
  const float* v2   = (const float*)d_in[10];
  const float* w3   = (const float*)d_in[11];
  const float* g3   = (const float*)d_in[12];
  const float* b3   = (const float*)d_in[13];
  const float* m3   = (const float*)d_in[14];
  const float* v3   = (const float*)d_in[15];
  const float* wout = (const float*)d_in[16];
  float* out = (float*)d_out;

  char* base = (char*)d_ws;
  size_t off = 0;
  auto take = [&](size_t bytes) -> char* {
    char* p = base + off;
    off += (bytes + 255) & ~(size_t)255;
    return p;
  };
  char* A0  = take((size_t)Bsz * Din / 2);
  char* Aa  = take((size_t)Bsz * Hid / 2);
  char* Ab  = take((size_t)Bsz * Hid / 2);
  char* W1s = take((size_t)Hid * Din / 2);
  char* W2s = take((size_t)Hid * Hid / 2);
  char* W3s = take((size_t)Hid * Hid / 2);
  float* a1  = (float*)take(Hid * 4);
  float* be1 = (float*)take(Hid * 4);
  float* a2  = (float*)take(Hid * 4);
  float* be2 = (float*)take(Hid * 4);
  float* a3  = (float*)take(Hid * 4);
  float* be3 = (float*)take(Hid * 4);

  hipMemsetAsync(d_out, 0, (size_t)out_size * sizeof(float), stream);

  prep_kernel<<<13336, 256, 0, stream>>>(
      x, w1, w2, w3,
      g1, b1, m1, v1, g2, b2, m2, v2, g3, b3, m3, v3,
      (unsigned*)A0, (unsigned*)W1s, (unsigned*)W2s, (unsigned*)W3s,
      a1, be1, a2, be2, a3, be3);

  // grid 1024: (16384/256) m-panels x (2048/128) n-panels, XCD-swizzled
  layer_mfma<Din, false><<<1024, 512, 0, stream>>>(A0, W1s, a1, be1, Aa,
                                                   nullptr, nullptr);
  layer_mfma<Hid, false><<<1024, 512, 0, stream>>>(Aa, W2s, a2, be2, Ab,
                                                   nullptr, nullptr);
  layer_mfma<Hid, true><<<1024, 512, 0, stream>>>(Ab, W3s, a3, be3, nullptr,
                                                  wout, out);
}